// Round 1
// baseline (706.139 us; speedup 1.0000x reference)
//
#include <hip/hip_runtime.h>
#include <hip/hip_bf16.h>

#define N_NODES   100000
#define N_EDGES   3200000
#define N_FEAT    128
#define HIDDEN    16
#define N_CLASSES 10
#define N_GRAPHS  64

// Workspace layout (float offsets):
//   deg/dinv : [0,        100000)   zeroed, deg then overwritten in-place by dinv
//   agg1     : [100000,  1700000)   zeroed
//   agg2     : [1700000, 2700000)   zeroed
//   h1       : [2700000, 4300000)
//   h2       : [4300000, 5300000)
// total 5.3M floats = 21.2 MB

__global__ __launch_bounds__(256) void k_deg(const int* __restrict__ dst,
                                             float* __restrict__ deg) {
    int i = blockIdx.x * 256 + threadIdx.x;
    if (i < N_EDGES) atomicAdd(&deg[dst[i]], 1.0f);
}

// 16 nodes per block; W1 and the x-tile staged in LDS. Also computes
// dinv[i] = rsqrt(deg[i]+1) in-place over deg.
__global__ __launch_bounds__(256) void k_gemm1(const float* __restrict__ x,
                                               const float* __restrict__ W1,
                                               float* __restrict__ h1,
                                               float* __restrict__ deg) {
    __shared__ float w[N_FEAT * HIDDEN];   // 8 KB
    __shared__ float xs[16 * N_FEAT];      // 8 KB
    int tid  = threadIdx.x;
    int base = blockIdx.x * 16;
    if (tid < 16) {
        int i = base + tid;
        deg[i] = rsqrtf(deg[i] + 1.0f);    // becomes dinv
    }
#pragma unroll
    for (int k = 0; k < 8; ++k) w[k * 256 + tid] = W1[k * 256 + tid];
#pragma unroll
    for (int k = 0; k < 8; ++k)
        xs[k * 256 + tid] = x[base * N_FEAT + k * 256 + tid];
    __syncthreads();
    int n = tid >> 4, c = tid & 15;
    const float* xr = &xs[n * N_FEAT];
    float acc = 0.f;
#pragma unroll 8
    for (int k = 0; k < N_FEAT; ++k) acc += xr[k] * w[k * HIDDEN + c];
    h1[(base + n) * HIDDEN + c] = acc;
}

// one thread per (edge, channel); 16 consecutive threads share an edge ->
// h1 gather and atomic target are contiguous 64B lines.
__global__ __launch_bounds__(256) void k_scatter16(const int* __restrict__ src,
                                                   const int* __restrict__ dst,
                                                   const float* __restrict__ dinv,
                                                   const float* __restrict__ h1,
                                                   float* __restrict__ agg1) {
    long long tid = (long long)blockIdx.x * 256 + threadIdx.x;
    int e = (int)(tid >> 4);
    int c = (int)(tid & 15);
    if (e >= N_EDGES) return;
    int s = src[e], d = dst[e];
    float coef = dinv[s] * dinv[d];
    atomicAdd(&agg1[d * HIDDEN + c], h1[s * HIDDEN + c] * coef);
}

// self-loop + bias + ReLU + (relu @ W2) -> h2  (b2 folded in at pooling)
__global__ __launch_bounds__(256) void k_layer2(const float* __restrict__ agg1,
                                                const float* __restrict__ h1,
                                                const float* __restrict__ dinv,
                                                const float* __restrict__ b1,
                                                const float* __restrict__ W2,
                                                float* __restrict__ h2) {
    __shared__ float w2[HIDDEN * N_CLASSES];
    __shared__ float b1s[HIDDEN];
    int tid = threadIdx.x;
    if (tid < HIDDEN * N_CLASSES) w2[tid] = W2[tid];
    if (tid < HIDDEN) b1s[tid] = b1[tid];
    __syncthreads();
    int i = blockIdx.x * 256 + tid;
    if (i >= N_NODES) return;
    float di = dinv[i], d2 = di * di;
    float r[HIDDEN];
    const float4* a4 = (const float4*)&agg1[i * HIDDEN];
    const float4* h4 = (const float4*)&h1[i * HIDDEN];
#pragma unroll
    for (int q = 0; q < 4; ++q) {
        float4 a = a4[q], h = h4[q];
        r[q * 4 + 0] = fmaxf(a.x + h.x * d2 + b1s[q * 4 + 0], 0.f);
        r[q * 4 + 1] = fmaxf(a.y + h.y * d2 + b1s[q * 4 + 1], 0.f);
        r[q * 4 + 2] = fmaxf(a.z + h.z * d2 + b1s[q * 4 + 2], 0.f);
        r[q * 4 + 3] = fmaxf(a.w + h.w * d2 + b1s[q * 4 + 3], 0.f);
    }
    float o[N_CLASSES];
#pragma unroll
    for (int j = 0; j < N_CLASSES; ++j) o[j] = 0.f;
#pragma unroll
    for (int c = 0; c < HIDDEN; ++c) {
        float rc = r[c];
#pragma unroll
        for (int j = 0; j < N_CLASSES; ++j) o[j] += rc * w2[c * N_CLASSES + j];
    }
#pragma unroll
    for (int j = 0; j < N_CLASSES; ++j) h2[i * N_CLASSES + j] = o[j];
}

__global__ __launch_bounds__(256) void k_scatter10(const int* __restrict__ src,
                                                   const int* __restrict__ dst,
                                                   const float* __restrict__ dinv,
                                                   const float* __restrict__ h2,
                                                   float* __restrict__ agg2) {
    long long tid = (long long)blockIdx.x * 256 + threadIdx.x;
    int e = (int)(tid >> 4);
    int c = (int)(tid & 15);
    if (e >= N_EDGES || c >= N_CLASSES) return;
    int s = src[e], d = dst[e];
    float coef = dinv[s] * dinv[d];
    atomicAdd(&agg2[d * N_CLASSES + c], h2[s * N_CLASSES + c] * coef);
}

// one block per graph; batch is sorted -> binary search the node range,
// block-reduce sums, then log_softmax straight to d_out.
__global__ __launch_bounds__(256) void k_pool(const float* __restrict__ agg2,
                                              const float* __restrict__ h2,
                                              const float* __restrict__ dinv,
                                              const float* __restrict__ b2,
                                              const int* __restrict__ batch,
                                              float* __restrict__ out) {
    __shared__ float red[N_CLASSES][256];
    int g = blockIdx.x, tid = threadIdx.x;
    int lo = 0, hi = N_NODES;
    while (lo < hi) { int m = (lo + hi) >> 1; if (batch[m] < g) lo = m + 1; else hi = m; }
    int start = lo;
    lo = 0; hi = N_NODES;
    while (lo < hi) { int m = (lo + hi) >> 1; if (batch[m] < g + 1) lo = m + 1; else hi = m; }
    int end = lo;

    float sum[N_CLASSES];
#pragma unroll
    for (int j = 0; j < N_CLASSES; ++j) sum[j] = 0.f;
    for (int i = start + tid; i < end; i += 256) {
        float di = dinv[i], d2 = di * di;
#pragma unroll
        for (int j = 0; j < N_CLASSES; ++j)
            sum[j] += agg2[i * N_CLASSES + j] + h2[i * N_CLASSES + j] * d2;
    }
#pragma unroll
    for (int j = 0; j < N_CLASSES; ++j) red[j][tid] = sum[j];
    __syncthreads();
    for (int s = 128; s > 0; s >>= 1) {
        if (tid < s) {
#pragma unroll
            for (int j = 0; j < N_CLASSES; ++j) red[j][tid] += red[j][tid + s];
        }
        __syncthreads();
    }
    if (tid == 0) {
        int cnt = end - start;
        float v[N_CLASSES];
        if (cnt > 0) {
            float inv = 1.f / (float)cnt;
#pragma unroll
            for (int j = 0; j < N_CLASSES; ++j) v[j] = red[j][0] * inv + b2[j];
        } else {
#pragma unroll
            for (int j = 0; j < N_CLASSES; ++j) v[j] = 0.f;
        }
        float m = v[0];
#pragma unroll
        for (int j = 1; j < N_CLASSES; ++j) m = fmaxf(m, v[j]);
        float l = 0.f;
#pragma unroll
        for (int j = 0; j < N_CLASSES; ++j) l += expf(v[j] - m);
        l = logf(l);
#pragma unroll
        for (int j = 0; j < N_CLASSES; ++j) out[g * N_CLASSES + j] = v[j] - m - l;
    }
}

extern "C" void kernel_launch(void* const* d_in, const int* in_sizes, int n_in,
                              void* d_out, int out_size, void* d_ws, size_t ws_size,
                              hipStream_t stream) {
    const float* x     = (const float*)d_in[0];
    const int*   edge  = (const int*)d_in[1];   // [2, E]
    const int*   batch = (const int*)d_in[2];
    const float* W1    = (const float*)d_in[3];
    const float* b1    = (const float*)d_in[4];
    const float* W2    = (const float*)d_in[5];
    const float* b2    = (const float*)d_in[6];
    float* out = (float*)d_out;
    float* ws  = (float*)d_ws;

    float* deg  = ws;             // then dinv
    float* agg1 = ws + 100000;
    float* agg2 = ws + 1700000;
    float* h1   = ws + 2700000;
    float* h2   = ws + 4300000;
    const int* srcp = edge;
    const int* dstp = edge + N_EDGES;

    hipMemsetAsync(d_ws, 0, 2700000ull * sizeof(float), stream);

    k_deg<<<N_EDGES / 256, 256, 0, stream>>>(dstp, deg);
    k_gemm1<<<N_NODES / 16, 256, 0, stream>>>(x, W1, h1, deg);
    k_scatter16<<<(N_EDGES * 16) / 256, 256, 0, stream>>>(srcp, dstp, deg, h1, agg1);
    k_layer2<<<(N_NODES + 255) / 256, 256, 0, stream>>>(agg1, h1, deg, b1, W2, h2);
    k_scatter10<<<(N_EDGES * 16) / 256, 256, 0, stream>>>(srcp, dstp, deg, h2, agg2);
    k_pool<<<N_GRAPHS, 256, 0, stream>>>(agg2, h2, deg, b2, batch, out);
}